// Round 20
// baseline (199.375 us; speedup 1.0000x reference)
//
#include <hip/hip_runtime.h>
#include <math.h>

// Problem constants
#define DIM   320
#define HD    40
#define NH    8
#define LQ    2048
#define BATCH 2
#define MROWS 4096
#define FFD   1280
#define FF2   2560

#define KSPLIT 2
#define KCHUNK (LQ/KSPLIT) // 1024
#define KT     32
#define NT     (KCHUNK/KT) // 32 tiles per block
#define NQROWS (BATCH*NH*LQ)  // 32768

#define LSCALE (0.15811388300841897f * 1.4426950408889634f)

typedef unsigned short ushort_t;
typedef unsigned int u32;
using bf16x8 = __attribute__((ext_vector_type(8))) short;
using f32x4  = __attribute__((ext_vector_type(4))) float;

#define AS1 __attribute__((address_space(1)))
#define AS3 __attribute__((address_space(3)))

static __device__ inline ushort_t f2bf(float f) {
  union { float f; unsigned u; } x{f};
  unsigned r = x.u + 0x7FFFu + ((x.u >> 16) & 1u);
  return (ushort_t)(r >> 16);
}
static __device__ inline float bf2f(ushort_t h) {
  union { unsigned u; float f; } x; x.u = ((unsigned)h) << 16; return x.f;
}

// ---------------- Weight convert/transpose to bf16 --------------------------
// R26: e==9 = ln1. R30: wo1 -> k-image. R32: e==10 = Wc GEMM from fp32
// inputs (bitwise-identical to the old wc_gemm two-step: same f2bf rounding,
// same MFMA order); its 25 blocks hide under convw's ~10K blocks (-1 launch).
#define OFF_WQKVT 0
#define OFF_WO1T  (960*320)
#define OFF_WO2T  (OFF_WO1T + 320*320)
#define OFF_WFF1T (OFF_WO2T + 320*320)
#define OFF_WFF2T (OFF_WFF1T + 320*2560)
#define OFF_WVHB  (OFF_WFF2T + 1280*320)
#define WBF_TOTAL (OFF_WVHB + 320*320)

#define AST 72

__global__ __launch_bounds__(256) void convw_kernel(
    const float* __restrict__ wq1, const float* __restrict__ wk1,
    const float* __restrict__ wv1, const float* __restrict__ wo1,
    const float* __restrict__ wo2, const float* __restrict__ wff1,
    const float* __restrict__ wff2, const float* __restrict__ wvh,
    ushort_t* __restrict__ dst, ushort_t* __restrict__ Kimg,
    const float* __restrict__ hidden, const float* __restrict__ ln1_g,
    const float* __restrict__ ln1_b, ushort_t* __restrict__ lnb,
    ushort_t* __restrict__ Wctb)
{
  __shared__ ushort_t As[64*AST];   // e==10 GEMM staging
  __shared__ ushort_t Bs[64*AST];
  __shared__ float tile[32][33];    // weight-conversion staging
  int e = blockIdx.y;
  if (e == 8) {                  // zero Kimg pad chunks: 16bh x 64t x 32rr x 3
    int f = blockIdx.x*256 + threadIdx.x;
    if (f < 98304) {
      int g3 = f/3, cidx = f - 3*g3;
      int rr = g3 & 31, tile_ = (g3 >> 5) & 63, bh = g3 >> 11;
      uint4 z = {0,0,0,0};
      *(uint4*)(Kimg + ((size_t)(bh*64 + tile_))*2048 + rr*64
                + (((5+cidx) ^ (rr&7)) << 3)) = z;
    }
    return;
  }
  if (e == 9) {                  // ln1: one wave per row
    int row  = blockIdx.x * 4 + (threadIdx.x >> 6);
    int lane = threadIdx.x & 63;
    const float* x = hidden + (size_t)row * DIM;
    float v[5];
    float s = 0.f;
#pragma unroll
    for (int i = 0; i < 5; ++i) { v[i] = x[lane + 64*i]; s += v[i]; }
#pragma unroll
    for (int off = 32; off >= 1; off >>= 1) s += __shfl_xor(s, off, 64);
    float mean = s * (1.0f/DIM);
    float sq = 0.f;
#pragma unroll
    for (int i = 0; i < 5; ++i) { float d = v[i] - mean; sq += d*d; }
#pragma unroll
    for (int off = 32; off >= 1; off >>= 1) sq += __shfl_xor(sq, off, 64);
    float rstd = rsqrtf(sq*(1.0f/DIM) + 1e-5f);
    ushort_t* y = lnb + (size_t)row * DIM;
#pragma unroll
    for (int i = 0; i < 5; ++i) {
      int c = lane + 64*i;
      y[c] = f2bf((v[i]-mean)*rstd*ln1_g[c] + ln1_b[c]);
    }
    return;
  }
  if (e == 10) {                 // Wc^T = wo2^T @ wvh^T from fp32 inputs
    int t = blockIdx.x;
    if (t >= 25) return;
    int bm = (t/5)*64, bn = (t%5)*64;
    int tid = threadIdx.x;
    int w = tid >> 6, lane = tid & 63, quad = lane >> 4, n16 = lane & 15;
    int wm = w >> 1, wn = w & 1;
    int ky = tid >> 2, x4 = (tid & 3) << 4;

    f32x4 acc00 = {0.f,0.f,0.f,0.f}, acc01 = acc00, acc10 = acc00, acc11 = acc00;

    for (int k0 = 0; k0 < DIM; k0 += 64) {
      __syncthreads();
      {
        // A[sr][k] = wo2[k][bm+sr]: transpose-convert wo2 cols bm..bm+63
        float va[16];
#pragma unroll
        for (int i = 0; i < 4; ++i)
          *(float4*)(va + 4*i) =
              *(const float4*)(wo2 + (size_t)(k0 + ky)*DIM + bm + x4 + 4*i);
#pragma unroll
        for (int j = 0; j < 16; ++j)
          As[(x4 + j)*AST + ky] = f2bf(va[j]);
        // B[sr][k] = wvh[bn+sr][k]: direct row convert
        float vb[16];
#pragma unroll
        for (int i = 0; i < 4; ++i)
          *(float4*)(vb + 4*i) =
              *(const float4*)(wvh + (size_t)(bn + ky)*DIM + k0 + x4 + 4*i);
        ushort_t tb[16];
#pragma unroll
        for (int j = 0; j < 16; ++j) tb[j] = f2bf(vb[j]);
        *(float4*)(Bs + ky*AST + x4)     = *(float4*)tb;
        *(float4*)(Bs + ky*AST + x4 + 8) = *(float4*)(tb + 8);
      }
      __syncthreads();
#pragma unroll
      for (int kk = 0; kk < 64; kk += 32) {
        bf16x8 fa0 = *(const bf16x8*)(As + (wm*32 +      n16)*AST + kk + quad*8);
        bf16x8 fa1 = *(const bf16x8*)(As + (wm*32 + 16 + n16)*AST + kk + quad*8);
        bf16x8 fb0 = *(const bf16x8*)(Bs + (wn*32 +      n16)*AST + kk + quad*8);
        bf16x8 fb1 = *(const bf16x8*)(Bs + (wn*32 + 16 + n16)*AST + kk + quad*8);
        acc00 = __builtin_amdgcn_mfma_f32_16x16x32_bf16(fa0, fb0, acc00, 0,0,0);
        acc01 = __builtin_amdgcn_mfma_f32_16x16x32_bf16(fa0, fb1, acc01, 0,0,0);
        acc10 = __builtin_amdgcn_mfma_f32_16x16x32_bf16(fa1, fb0, acc10, 0,0,0);
        acc11 = __builtin_amdgcn_mfma_f32_16x16x32_bf16(fa1, fb1, acc11, 0,0,0);
      }
    }

    f32x4 accs[2][2] = {{acc00, acc01},{acc10, acc11}};
#pragma unroll
    for (int s = 0; s < 2; ++s)
#pragma unroll
      for (int tt = 0; tt < 2; ++tt) {
        int c = bn + wn*32 + tt*16 + n16;     // k of cross
#pragma unroll
        for (int i = 0; i < 4; ++i) {
          int r = bm + wm*32 + s*16 + quad*4 + i;   // cross output col
          Wctb[((size_t)(c >> 5)*320 + r)*32
               + ((((c >> 3) & 3) ^ (r & 3)) << 3) + (c & 7)] = f2bf(accs[s][tt][i]);
        }
      }
    return;
  }
  const float* src; int K, N; size_t doff; int tr = 1; float scale = 1.f;
  switch (e) {
    case 0: src=wq1;  K=320;  N=320;  doff=OFF_WQKVT; scale=LSCALE; break;
    case 1: src=wk1;  K=320;  N=320;  doff=OFF_WQKVT + 320*320;  break;
    case 2: src=wv1;  K=320;  N=320;  doff=OFF_WQKVT + 2*320*320;break;
    case 3: src=wo1;  K=320;  N=320;  doff=OFF_WO1T; tr=2;       break;
    case 4: src=wo2;  K=320;  N=320;  doff=OFF_WO2T;             break;
    case 5: src=wff1; K=320;  N=2560; doff=OFF_WFF1T;            break;
    case 6: src=wff2; K=1280; N=320;  doff=OFF_WFF2T;            break;
    default: src=wvh; K=320;  N=320;  doff=OFF_WVHB; tr=0;       break;
  }
  int ntN = N/32;
  int nt_total = (K/32)*ntN;
  int t = blockIdx.x;
  if (t >= nt_total) return;
  int kt = t / ntN, nt = t - kt*ntN;
  int tx = threadIdx.x & 31, ty = threadIdx.x >> 5;
  ushort_t* d = dst + doff;
#pragma unroll
  for (int i = 0; i < 4; ++i) {
    int r = ty + 8*i;
    tile[r][tx] = src[(size_t)(kt*32+r)*N + nt*32+tx] * scale;
  }
  __syncthreads();
  if (tr == 1) {
#pragma unroll
    for (int i = 0; i < 4; ++i) {
      int r = ty + 8*i;
      d[(size_t)(nt*32+r)*K + kt*32+tx] = f2bf(tile[tx][r]);
    }
  } else if (tr == 2) {   // k-blocked swizzled B-image: element (k, c)
#pragma unroll
    for (int i = 0; i < 4; ++i) {
      int r = ty + 8*i;
      int k = kt*32 + r, c = nt*32 + tx;
      d[((size_t)kt*320 + c)*32 + ((((k >> 3) & 3) ^ (c & 3)) << 3) + (k & 7)]
          = f2bf(tile[r][tx]);
    }
  } else {
#pragma unroll
    for (int i = 0; i < 4; ++i) {
      int r = ty + 8*i;
      d[(size_t)(kt*32+r)*N + nt*32+tx] = f2bf(tile[r][tx]);
    }
  }
}

// ---------------- bf16 MFMA GEMM (TN), 64x64 tile, BK=64 — ff2 only ---------
__global__ __launch_bounds__(256) void mgemm(
    const ushort_t* __restrict__ A, int lda,
    const ushort_t* __restrict__ Bt, int ldb,
    const float* __restrict__ bias,
    const float* __restrict__ R,
    float* __restrict__ Cf, ushort_t* __restrict__ Cb, int ldc,
    int K)
{
  __shared__ ushort_t As[64*AST];
  __shared__ ushort_t Bs[64*AST];
  int tid = threadIdx.x;
  int w = tid >> 6, lane = tid & 63, quad = lane >> 4, n16 = lane & 15;
  int wm = w >> 1, wn = w & 1;
  int bm = blockIdx.y * 64, bn = blockIdx.x * 64;
  int sr = tid >> 2, sc = (tid & 3) << 4;
  const ushort_t* Ag = A  + (size_t)(bm + sr)*lda + sc;
  const ushort_t* Bg = Bt + (size_t)(bn + sr)*ldb + sc;

  f32x4 acc00 = {0.f,0.f,0.f,0.f}, acc01 = acc00, acc10 = acc00, acc11 = acc00;

  float4 av0 = *(const float4*)(Ag);
  float4 av1 = *(const float4*)(Ag + 8);
  float4 bv0 = *(const float4*)(Bg);
  float4 bv1 = *(const float4*)(Bg + 8);
  for (int k0 = 0; k0 < K; k0 += 64) {
    __syncthreads();
    *(float4*)(As + sr*AST + sc)     = av0;
    *(float4*)(As + sr*AST + sc + 8) = av1;
    *(float4*)(Bs + sr*AST + sc)     = bv0;
    *(float4*)(Bs + sr*AST + sc + 8) = bv1;
    __syncthreads();
    if (k0 + 64 < K) {
      av0 = *(const float4*)(Ag + k0 + 64);
      av1 = *(const float4*)(Ag + k0 + 72);
      bv0 = *(const float4*)(Bg + k0 + 64);
      bv1 = *(const float4*)(Bg + k0 + 72);
    }
#pragma unroll
    for (int kk = 0; kk < 64; kk += 32) {
      bf16x8 fa0 = *(const bf16x8*)(As + (wm*32 +      n16)*AST + kk + quad*8);
      bf16x8 fa1 = *(const bf16x8*)(As + (wm*32 + 16 + n16)*AST + kk + quad*8);
      bf16x8 fb0 = *(const bf16x8*)(Bs + (wn*32 +      n16)*AST + kk + quad*8);
      bf16x8 fb1 = *(const bf16x8*)(Bs + (wn*32 + 16 + n16)*AST + kk + quad*8);
      acc00 = __builtin_amdgcn_mfma_f32_16x16x32_bf16(fa0, fb0, acc00, 0,0,0);
      acc01 = __builtin_amdgcn_mfma_f32_16x16x32_bf16(fa0, fb1, acc01, 0,0,0);
      acc10 = __builtin_amdgcn_mfma_f32_16x16x32_bf16(fa1, fb0, acc10, 0,0,0);
      acc11 = __builtin_amdgcn_mfma_f32_16x16x32_bf16(fa1, fb1, acc11, 0,0,0);
    }
  }

  f32x4 accs[2][2] = {{acc00, acc01},{acc10, acc11}};
#pragma unroll
  for (int s = 0; s < 2; ++s)
#pragma unroll
    for (int t = 0; t < 2; ++t) {
      int c = bn + wn*32 + t*16 + n16;
      float bb = bias ? bias[c] : 0.f;
#pragma unroll
      for (int i = 0; i < 4; ++i) {
        int r = bm + wm*32 + s*16 + quad*4 + i;
        float v = accs[s][t][i] + bb;
        if (R)  v += R[(size_t)r*ldc + c];
        if (Cf) Cf[(size_t)r*ldc + c] = v;
        if (Cb) Cb[(size_t)r*ldc + c] = f2bf(v);
      }
    }
}

// -------- fused merge + o1 + ln2 + cross + ln3 (R31) ------------------------
__global__ __launch_bounds__(256) void o1cross_ln(
    const float* __restrict__ Pl, const ushort_t* __restrict__ Pacc,
    const ushort_t* __restrict__ Wo1tb,
    const float* __restrict__ bo1, const float* __restrict__ hidden,
    const float* __restrict__ g2, const float* __restrict__ b2,
    const ushort_t* __restrict__ Wctb, const float* __restrict__ bo2,
    const float* __restrict__ g3, const float* __restrict__ b3,
    float* __restrict__ h2, ushort_t* __restrict__ lnb)
{
  __shared__ ushort_t Asm[16*328];      // 10.25 KB
  __shared__ ushort_t Bsm[2*10240];     // 40 KB, double-buffered 32-k slabs
  __shared__ float    sred[4][16][2];
  __shared__ float    fstat[16][2];
  int tid = threadIdx.x;
  int w = tid >> 6, lane = tid & 63, quad = lane >> 4, n16 = lane & 15;
  int r0 = blockIdx.x * 16;

  // ---- Phase A: inline KSPLIT=2 merge -> normalized attn rows into Asm ----
  {
    int ar = tid >> 4, aj = tid & 15;
    int r = r0 + ar;
    int b = r >> 11, qi = r & (LQ-1);
    int h = aj >> 1, off = (aj & 1)*20;
    size_t idx = (size_t)(b*8 + h)*LQ + qi;
    float L = Pl[idx] + Pl[(size_t)NQROWS + idx];
    float inv = 1.0f / L;
    const ushort_t* p0 = Pacc + idx*40 + off;
    const ushort_t* p1 = Pacc + ((size_t)NQROWS + idx)*40 + off;
    ushort_t tb[20];
#pragma unroll
    for (int i = 0; i < 5; ++i) {
      ushort_t b0[4], b1[4];
      *(uint2*)b0 = *(const uint2*)(p0 + 4*i);
      *(uint2*)b1 = *(const uint2*)(p1 + 4*i);
#pragma unroll
      for (int j = 0; j < 4; ++j)
        tb[4*i+j] = f2bf((bf2f(b0[j]) + bf2f(b1[j])) * inv);
    }
#pragma unroll
    for (int i = 0; i < 5; ++i)
      *(uint2*)(Asm + ar*328 + aj*20 + 4*i) = *(uint2*)(tb + 4*i);
  }

#define STAGEB(BASE, BUF, KB) { \
  const ushort_t* src_ = (BASE) + (size_t)(KB)*10240; \
  _Pragma("unroll") \
  for (int i = 0; i < 5; ++i) { \
    __builtin_amdgcn_global_load_lds( \
        (const AS1 u32*)(src_ + i*2048 + w*512 + lane*8), \
        (AS3 u32*)(Bsm + (BUF)*10240 + i*2048 + w*512), 16, 0, 0); \
  } }

  f32x4 acc[5];
#pragma unroll
  for (int t = 0; t < 5; ++t) acc[t] = f32x4{0.f,0.f,0.f,0.f};

  // ---- GEMM1: attn @ wo1-image ----
  STAGEB(Wo1tb, 0, 0);
  __syncthreads();              // Asm written (lgkm) + slab0 (vmcnt)
  int bbuf = 0;
  for (int kb = 0; kb < 10; ++kb) {
    if (kb + 1 < 10) STAGEB(Wo1tb, bbuf^1, kb + 1);
    const ushort_t* Bb = Bsm + bbuf*10240;
    bf16x8 fa = *(const bf16x8*)(Asm + n16*328 + kb*32 + quad*8);
#pragma unroll
    for (int t = 0; t < 5; ++t) {
      int c = w*80 + t*16 + n16;
      bf16x8 fb = *(const bf16x8*)(Bb + c*32 + ((quad ^ (c & 3)) << 3));
      acc[t] = __builtin_amdgcn_mfma_f32_16x16x32_bf16(fa, fb, acc[t], 0,0,0);
    }
    __syncthreads();
    bbuf ^= 1;
  }

  // issue Wc slab 0 early (drained by the pre-GEMM2 barrier)
  STAGEB(Wctb, 0, 0);

  // ---- Epilogue1: h1 = acc + bo1 + hidden (registers); ln2 stats ----
  float h1v[5][4];
  float ss[4] = {0,0,0,0}, qq[4] = {0,0,0,0};
#pragma unroll
  for (int t = 0; t < 5; ++t) {
    int c = w*80 + t*16 + n16;
    float bb = bo1[c];
#pragma unroll
    for (int i = 0; i < 4; ++i) {
      int r = r0 + quad*4 + i;
      float v = acc[t][i] + bb + hidden[(size_t)r*DIM + c];
      h1v[t][i] = v;
      ss[i] += v; qq[i] += v*v;
    }
  }
#pragma unroll
  for (int off = 1; off < 16; off <<= 1)
#pragma unroll
    for (int i = 0; i < 4; ++i) {
      ss[i] += __shfl_xor(ss[i], off, 64);
      qq[i] += __shfl_xor(qq[i], off, 64);
    }
  if (n16 == 0)
#pragma unroll
    for (int i = 0; i < 4; ++i) {
      sred[w][quad*4 + i][0] = ss[i];
      sred[w][quad*4 + i][1] = qq[i];
    }
  __syncthreads();
  if (tid < 16) {
    float S = sred[0][tid][0]+sred[1][tid][0]+sred[2][tid][0]+sred[3][tid][0];
    float Q = sred[0][tid][1]+sred[1][tid][1]+sred[2][tid][1]+sred[3][tid][1];
    float mm = S*(1.f/DIM);
    fstat[tid][0] = mm;
    fstat[tid][1] = rsqrtf(fmaxf(Q*(1.f/DIM) - mm*mm, 0.f) + 1e-5f);
  }
  __syncthreads();
  // write ln2(h1) bf16 into Asm (fragment-scattered b16 stores)
#pragma unroll
  for (int t = 0; t < 5; ++t) {
    int c = w*80 + t*16 + n16;
    float gg = g2[c], bbv = b2[c];
#pragma unroll
    for (int i = 0; i < 4; ++i) {
      int rr = quad*4 + i;
      Asm[rr*328 + c] = f2bf((h1v[t][i] - fstat[rr][0])*fstat[rr][1]*gg + bbv);
    }
  }
#pragma unroll
  for (int t = 0; t < 5; ++t) acc[t] = f32x4{0.f,0.f,0.f,0.f};
  __syncthreads();              // Asm ln2 writes visible + Wc slab0 staged

  // ---- GEMM2: ln2(h1) @ Wc-image ----
  bbuf = 0;
  for (int kb = 0; kb < 10; ++kb) {
    if (kb + 1 < 10) STAGEB(Wctb, bbuf^1, kb + 1);
    const ushort_t* Bb = Bsm + bbuf*10240;
    bf16x8 fa = *(const bf16x8*)(Asm + n16*328 + kb*32 + quad*8);
#pragma unroll
    for (int t = 0; t < 5; ++t) {
      int c = w*80 + t*16 + n16;
      bf16x8 fb = *(const bf16x8*)(Bb + c*32 + ((quad ^ (c & 3)) << 3));
      acc[t] = __builtin_amdgcn_mfma_f32_16x16x32_bf16(fa, fb, acc[t], 0,0,0);
    }
    __syncthreads();
    bbuf ^= 1;
  }
#undef STAGEB

  // ---- Epilogue2: h2 = acc + bo2 + h1; ln3 stats; write h2 fp32, lnb bf16 --
  float hv[5][4];
  float ss2[4] = {0,0,0,0}, qq2[4] = {0,0,0,0};
#pragma unroll
  for (int t = 0; t < 5; ++t) {
    int c = w*80 + t*16 + n16;
    float bb = bo2[c];
#pragma unroll
    for (int i = 0; i < 4; ++i) {
      int r = r0 + quad*4 + i;
      float v = acc[t][i] + bb + h1v[t][i];
      hv[t][i] = v;
      h2[(size_t)r*DIM + c] = v;
      ss2[i] += v; qq2[i] += v*v;
    }
  }
#pragma unroll
  for (int off = 1; off < 16; off <<= 1)
#pragma unroll
    for (int i = 0; i < 4; ++i) {
      ss2[i] += __shfl_xor(ss2[i], off, 64);
      qq2[i] += __shfl_xor(qq2[i], off, 64);
    }
  if (n16 == 0)
#pragma unroll
    for (int i = 0; i < 4; ++i) {
      sred[w][quad*4 + i][0] = ss2[i];
      sred[w][quad*4 + i][1] = qq2[i];
    }
  __syncthreads();
  if (tid < 16) {
    float S = sred[0][tid][0]+sred[1][tid][0]+sred[2][tid][0]+sred[3][tid][0];
    float Q = sred[0][tid][1]+sred[1][tid][1]+sred[2][tid][1]+sred[3][tid][1];
    float mm = S*(1.f/DIM);
    fstat[tid][0] = mm;
    fstat[tid][1] = rsqrtf(fmaxf(Q*(1.f/DIM) - mm*mm, 0.f) + 1e-5f);
  }
  __syncthreads();
#pragma unroll
  for (int t = 0; t < 5; ++t) {
    int c = w*80 + t*16 + n16;
    float gg = g3[c], bb = b3[c];
#pragma unroll
    for (int i = 0; i < 4; ++i) {
      int rr = quad*4 + i;
      lnb[(size_t)(r0 + rr)*DIM + c] =
          f2bf((hv[t][i] - fstat[rr][0])*fstat[rr][1]*gg + bb);
    }
  }
}

// --------- qkv GEMM 128x64 + fused K/V-image epilogue (R19, R21: BK=64) -----
__global__ __launch_bounds__(256) void mgemm128_qkv(
    const ushort_t* __restrict__ A, const ushort_t* __restrict__ Bt,
    ushort_t* __restrict__ Qb, ushort_t* __restrict__ Kimg,
    ushort_t* __restrict__ Vimg)
{
  __shared__ ushort_t As[128*AST];   // 18 KB
  __shared__ ushort_t Bs[64*AST];    // 9 KB
  int tid = threadIdx.x;
  int w = tid >> 6, lane = tid & 63, quad = lane >> 4, n16 = lane & 15;
  int wm = w >> 1, wn = w & 1;
  int bm = blockIdx.y * 128, bn = blockIdx.x * 64;
  int ar = tid >> 2, ac = (tid & 3) << 4;
  const ushort_t* Ag0 = A  + (size_t)(bm + ar)*DIM + ac;
  const ushort_t* Ag1 = A  + (size_t)(bm + 64 + ar)*DIM + ac;
  const ushort_t* Bg  = Bt + (size_t)(bn + ar)*DIM + ac;

  f32x4 acc[4][2];
#pragma unroll
  for (int s = 0; s < 4; ++s)
#pragma unroll
    for (int t = 0; t < 2; ++t) acc[s][t] = f32x4{0.f,0.f,0.f,0.f};

  float4 a00 = *(const float4*)(Ag0);
  float4 a01 = *(const float4*)(Ag0 + 8);
  float4 a10 = *(const float4*)(Ag1);
  float4 a11 = *(const float4*)(Ag1 + 8);
  float4 b0  = *(const float4*)(Bg);
  float4 b1  = *(const float4*)(Bg + 8);
  for (int k0 = 0; k0 < DIM; k0 += 64) {
    __syncthreads();
    *(float4*)(As + ar*AST + ac)          = a00;
    *(float4*)(As + ar*AST + ac + 8)      = a01;
    *(float4*)(As + (64+ar)*AST + ac)     = a10;
    *(float4*)(As + (64+ar)*AST + ac + 8) = a11;
    *(float4*)(Bs + ar*AST + ac)          = b0;
    *(float4*)(Bs + ar*AST + ac + 8)      = b1;
    __syncthreads();
    if (k0 + 64 < DIM) {
      a00 = *(const float4*)(Ag0 + k0 + 64);
      a01 = *(const float4*)(Ag0 + k0 + 72);
      a10 = *(const float4*)(Ag1 + k0 + 64);
      a11 = *(const float4*)(Ag1 + k0 + 72);
      b0  = *(const float4*)(Bg  + k0 + 64);
      b1  = *(const float4*)(Bg  + k0 + 72);
    }
#pragma unroll
    for (int kk = 0; kk < 64; kk += 32) {
      bf16x8 fa[4], fb[2];
#pragma unroll
      for (int s = 0; s < 4; ++s)
        fa[s] = *(const bf16x8*)(As + (wm*64 + s*16 + n16)*AST + kk + quad*8);
#pragma unroll
      for (int t = 0; t < 2; ++t)
        fb[t] = *(const bf16x8*)(Bs + (wn*32 + t*16 + n16)*AST + kk + quad*8);
#pragma unroll
      for (int s = 0; s < 4; ++s)
#pragma unroll
        for (int t = 0; t < 2; ++t)
          acc[s][t] = __builtin_amdgcn_mfma_f32_16x16x32_bf16(fa[s], fb[t], acc[s][t], 0,0,0);
    }
  }

  int b8 = (bm >> 11) << 3;   // batch*8
  if (bn < 320) {             // ---- Q region -> Qb[r*320 + c]
#pragma unroll
    for (int s = 0; s < 4; ++s)
#pragma unroll
      for (int t = 0; t < 2; ++t) {
        int c = bn + wn*32 + t*16 + n16;
#pragma unroll
        for (int i = 0; i < 4; ++i) {
          int r = bm + wm*64 + s*16 + quad*4 + i;
          Qb[(size_t)r*320 + c] = f2bf(acc[s][t][i]);
        }
      }
  } else if (bn < 640) {      // ---- K region -> Kimg swizzled
#pragma unroll
    for (int t = 0; t < 2; ++t) {
      int c = bn + wn*32 + t*16 + n16 - 320;
      int hK = c / 40, d = c - hK*40;
#pragma unroll
      for (int s = 0; s < 4; ++s)
#pragma unroll
        for (int i = 0; i < 4; ++i) {
          int r = bm + wm*64 + s*16 + quad*4 + i;
          int l = r & 2047, tl = l >> 5, rr = l & 31;
          Kimg[((size_t)((b8 + hK)*64 + tl))*2048 + rr*64
               + (((d >> 3) ^ (rr & 7)) << 3) + (d & 7)] = f2bf(acc[s][t][i]);
        }
    }
  } else {                    // ---- V region -> Vimg swizzled, pair-packed
#pragma unroll
    for (int t = 0; t < 2; ++t) {
      int c = bn + wn*32 + t*16 + n16 - 640;
      int hV = c / 40, d = c - hV*40;
#pragma unroll
      for (int s = 0; s < 4; ++s) {
        int l0 = (bm + wm*64 + s*16 + quad*4) & 2047;
        int tl = l0 >> 5, p0 = (l0 & 31) >> 1;
        ushort_t* vb = Vimg + ((size_t)((b8 + hV)*64 + tl))*1536 + d*32;
#pragma unroll
        for (int j = 0; j < 2; ++j) {
          int p = p0 + j;
          unsigned val = (unsigned)f2bf(acc[s][t][2*j])
                       | ((unsigned)f2bf(acc[s][t][2*j+1]) << 16);
          *(unsigned*)(vb + (((p >> 2) ^ (d & 3)) << 3) + ((p & 3) << 1)) = val;
        }
      }
    }
  }
}

// -------- ff1 GEMM 128x64 + fused GEGLU (R21: BK=64) ------------------------
__global__ __launch_bounds__(256) void ff1_geglu(
    const ushort_t* __restrict__ A, const ushort_t* __restrict__ Bt,
    const float* __restrict__ bias, ushort_t* __restrict__ Og)
{
  __shared__ ushort_t As[128*AST];   // 18 KB
  __shared__ ushort_t Bxs[64*AST];   // 9 KB
  __shared__ ushort_t Bgs[64*AST];   // 9 KB
  int tid = threadIdx.x;
  int w = tid >> 6, lane = tid & 63, quad = lane >> 4, n16 = lane & 15;
  int wm = w >> 1, wn = w & 1;
  int bm = blockIdx.y * 128, bn = blockIdx.x * 64;
  int ar = tid >> 2, ac = (tid & 3) << 4;
  const ushort_t* Ag0 = A  + (size_t)(bm + ar)*DIM + ac;
  const ushort_t* Ag1 = A  + (size_t)(bm + 64 + ar)*DIM + ac;
  const ushort_t* Bxg = Bt + (size_t)(bn + ar)*DIM + ac;
  const ushort_t* Bgg = Bt + (size_t)(bn + FFD + ar)*DIM + ac;

  f32x4 ax[4][2], ag[4][2];
#pragma unroll
  for (int s = 0; s < 4; ++s)
#pragma unroll
    for (int t = 0; t < 2; ++t) { ax[s][t] = f32x4{0.f,0.f,0.f,0.f}; ag[s][t] = ax[s][t]; }

  float4 a00 = *(const float4*)(Ag0);
  float4 a01 = *(const float4*)(Ag0 + 8);
  float4 a10 = *(const float4*)(Ag1);
  float4 a11 = *(const float4*)(Ag1 + 8);
  float4 bx0 = *(const float4*)(Bxg);
  float4 bx1 = *(const float4*)(Bxg + 8);
  float4 bg0 = *(const float4*)(Bgg);
  float4 bg1 = *(const float4*)(Bgg + 8);
  for (int k0 = 0; k0 < DIM; k0 += 64) {
    __syncthreads();
    *(float4*)(As  + ar*AST + ac)          = a00;
    *(float4*)(As  + ar*AST + ac + 8)      = a01;
    *(float4*)(As  + (64+ar)*AST + ac)     = a10;
    *(float4*)(As  + (64+ar)*AST + ac + 8) = a11;
    *(float4*)(Bxs + ar*AST + ac)          = bx0;
    *(float4*)(Bxs + ar*AST + ac + 8)      = bx1;
    *(float4*)(Bgs + ar*AST + ac)          = bg0;
    *(float4*)(Bgs + ar*AST + ac + 8)      = bg1;
    __syncthreads();
    if (k0 + 64 < DIM) {
      a00 = *(const float4*)(Ag0 + k0 + 64);
      a01 = *(const float4*)(Ag0 + k0 + 72);
      a10 = *(const float4*)(Ag1 + k0 + 64);
      a11 = *(const float4*)(Ag1 + k0 + 72);
      bx0 = *(const float4*)(Bxg + k0 + 64);
      bx1 = *(const float4*)(Bxg + k0 + 72);
      bg0 = *(const float4*)(Bgg + k0 + 64);
      bg1 = *(const float4*)(Bgg + k0 + 72);
    }
#pragma unroll
    for (int kk = 0; kk < 64; kk += 32) {
      bf16x8 fa[4], fx[2], fg[2];
#pragma unroll
      for (int s = 0; s < 4; ++s)
        fa[s] = *(const bf16x8*)(As + (wm*64 + s*16 + n16)*AST + kk + quad*8);
#pragma unroll
      for (int t = 0; t < 2; ++t) {
        fx[t] = *(const bf16x8*)(Bxs + (wn*32 + t*16 + n16)*AST + kk + quad*8);
        fg[t] = *(const bf16x8*)(Bgs + (wn*32 + t*16 + n16)*AST + kk + quad*8);
      }
#pragma unroll
      for (int s = 0; s < 4; ++s)
#pragma unroll
        for (int t = 0; t < 2; ++t) {
          ax[s][t] = __builtin_amdgcn_mfma_f32_16x16x32_bf16(fa[s], fx[t], ax[s][t], 0,0,0);
          ag[s][t] = __builtin_amdgcn_mfma_f32_16x16x32_bf16(fa[s], fg[t], ag[s][t], 0,0,0);
        }
    }
  }

  const float kk2 = 0.7071067811865476f;
#pragma unroll
  for (int s = 0; s < 4; ++s)
#pragma unroll
    for (int t = 0; t < 2; ++t) {
      int c = bn + wn*32 + t*16 + n16;
      float bx = bias[c], bg = bias[c + FFD];
#pragma unroll
      for (int i = 0; i < 4; ++i) {
        int r = bm + wm*64 + s*16 + quad*4 + i;
        float xx = ax[s][t][i] + bx;
        float gg = ag[s][t][i] + bg;
        Og[(size_t)r*FFD + c] = f2bf(xx * 0.5f * gg * (1.f + erff(gg * kk2)));
      }
    }
}

// ---------------- MFMA flash attention (R20 super-stage, KSPLIT=2) ----------
#define TILE_K_SH 2048
#define TILE_V_SH 1536
#define TILE_SH   (TILE_K_SH + TILE_V_SH)

__global__ __launch_bounds__(256, 2) void attn_mfma(
    const ushort_t* __restrict__ Qb, const ushort_t* __restrict__ Kimg,
    const ushort_t* __restrict__ Vimg,
    float* __restrict__ Pl, ushort_t* __restrict__ Pacc)
{
  __shared__ ushort_t lds[4*TILE_SH];      // 28672 B, 4 tile-slots
  int tid  = threadIdx.x;
  int w    = tid >> 6;
  int lane = tid & 63;
  int quad = lane >> 4;
  int n16  = lane & 15;

  int blk  = blockIdx.x;
  int bh   = (blk & 7) | (((blk >> 3) & 1) << 3);
  int rest = blk >> 4;
  int qt   = rest & 15;
  int ks   = rest >> 4;           // 0..KSPLIT-1
  int b = bh >> 3, h = bh & 7;

  const ushort_t* qrowa = Qb + (size_t)(b*LQ + qt*128 + w*32 + n16)*320 + h*HD;
  const ushort_t* qrowb = qrowa + 16*320;
  bf16x8 qf0a = *(const bf16x8*)(qrowa + quad*8);
  bf16x8 qf1a = *(const bf16x8*)(qrowa + 32);
  bf16x8 qf0b = *(const bf16x8*)(qrowb + quad*8);
  bf16x8 qf1b = *(const bf16x8*)(qrowb + 32);

  const ushort_t* Ktb = Kimg + ((size_t)bh*64 + ks*NT)*TILE_K_SH;
  const ushort_t* Vtb = Vimg + ((size_t)bh*64 + ks*NT)*TILE_V_SH;

  int swk0 = (quad ^ (n16 & 7)) << 3;
  int swk1 = ((quad + 4) ^ (n16 & 7)) << 3;
  int kof0 = n16*64 + swk0;
  int kof1 = n16*64 + swk1;
  int kof2 = (16+n16)*64 + swk0;
  int kof3 = (16+n16)*64 + swk1;
  int swv  = (quad ^ (n16 & 3)) << 3;
  int vof0 = n16*32 + swv;
  int vof1 = (16+n16)*32 + swv;
  int vof2 = (32+n16)*32 + swv;

  f32x4 o0a = {0.f,0.f,0.f,0.f}, o1a = o0a, o2a = o0a;
  f32x4 o0b = o0a, o1b = o0a, o2b = o0a;
  f32x4 la0a = o0a, la1a = o0a, la0b = o0a, la1b = o0a;

#define CVTPK(D, LO, HI) \
  asm("v_cvt_pk_bf16_f32 %0, %1, %2" : "=v"(D) : "v"(LO), "v"(HI))
#define PSWAP32(X, Y) \
  asm("v_permlane32_swap_b32 %0, %1" : "+v"(X), "+v"(Y))
#define PSWAP16(X, Y) \
  asm("v_permlane16_swap_b32 %0, %1" : "+v"(X), "+v"(Y))

#define STAGE(SLOT, T) { \
  const ushort_t* ks_ = Ktb + (size_t)(T)*TILE_K_SH + w*512 + lane*8; \
  ushort_t* kd_ = lds + (SLOT)*TILE_SH + w*512; \
  __builtin_amdgcn_global_load_lds( \
      (const AS1 u32*)ks_, (AS3 u32*)kd_, 16, 0, 0); \
  if (w < 3) { \
    const ushort_t* vs_ = Vtb + (size_t)(T)*TILE_V_SH + w*512 + lane*8; \
    ushort_t* vd_ = lds + (SLOT)*TILE_SH + TILE_K_SH + w*512; \
    __builtin_amdgcn_global_load_lds( \
        (const AS1 u32*)vs_, (AS3 u32*)vd_, 16, 0, 0); \
  } }

#define HALF(Q0F, Q1F, LA0, LA1, FRAG) \
  bf16x8 FRAG; { \
  f32x4 st0 = {-8.f,-8.f,-8.f,-8.f}; f32x4 st1 = st0; \
  st0 = __builtin_amdgcn_mfma_f32_16x16x32_bf16(K00, Q0F, st0, 0,0,0); \
  st1 = __builtin_amdgcn_mfma_f32_16x16x32_bf16(K10, Q0F, st1, 0,0,0); \
  st0 = __builtin_amdgcn_mfma_f32_16x16x32_bf16(K01, Q1F, st0, 0,0,0); \
  st1 = __builtin_amdgcn_mfma_f32_16x16x32_bf16(K11, Q1F, st1, 0,0,0); \
  f32x4 p0, p1; \
  _Pragma("unroll") \
  for (int r = 0; r < 4; ++r) { p0[r] = exp2f(st0[r]); p1[r] = exp2f(st1[r]); } \
  LA0 += p0; LA1 += p1; \
  unsigned d0, d1, d2, d3; \
  CVTPK(d0, p0[0], p0[1]); CVTPK(d1, p0[2], p0[3]); \
  CVTPK(d2, p1[0], p1[1]); CVTPK(d3, p1[2], p1[3]); \
  PSWAP32(d0, d2); PSWAP16(d0, d2); \
  PSWAP32(d1, d3); PSWAP16(d1, d3); \
  union { unsigned u[4]; bf16x8 v; } fr_; \
  fr_.u[0] = d0; fr_.u[1] = d1; fr_.u[2] = d2; fr_.u[3] = d3; \
  FRAG = fr_.v; }

#define CTILE(SLOT) { \
  const ushort_t* Kb_ = lds + (SLOT)*TILE_SH; \
  const ushort_t* Vb_ = Kb_ + TILE_K_SH; \
  bf16x8 K00 = *(const bf16x8*)(Kb_ + kof0); \
  bf16x8 K01 = *(const bf16x8*)(Kb_ + kof1); \
  bf16x8 K10 = *(const bf16x8*)(Kb_ + kof2); \
  bf16x8 K11 = *(const bf16x8*)(Kb_ + kof3); \
  bf16x8 V0  = *(const bf16x8*)(Vb_ + vof0); \
  bf16x8 V1  = *(const bf16x8*)(Vb_ + vof1); \
  bf16x8 V2  = *(const bf16x8*)(Vb_ + vof2); \
  HALF(qf0a, qf1a, la0a, la1a, fragA) \
  HALF(qf0b, qf1b, la0b, la1b, fragB) \
  o0a = __builtin_amdgcn_mfma_f32_16x16x32_bf16(fragA, V0, o0a, 0,0,0); \
  o0b = __builtin_amdgcn_mfma_f32_16x16x32_bf16(fragB, V0, o0b, 0,0,0); \
  o1a = __builtin_amdgcn_mfma_f32_16x16x32_bf16(fragA, V1, o1a, 0,0,0); \
  o1b = __builtin_amdgcn_mfma_f32_16x16x32_bf16(fragB, V1, o1b, 0,0,0); \
  o2a = __builtin_amdgcn_mfma_f32_16x16x32_bf16(fragA, V2, o2a, 0,0,0); \
  o2b = __builtin_amdgcn_mfma_f32_16x16x32_bf16(fragB, V2, o2b, 0,0,0); }

  STAGE(0, 0); STAGE(1, 1);
  __syncthreads();
  for (int s = 0; s < NT/2; ++s) {
    int sb = s & 1;
    if (s + 1 < NT/2) {
      STAGE((sb^1)*2,     2*s + 2);
      STAGE((sb^1)*2 + 1, 2*s + 3);
    }
    CTILE(sb*2);
    CTILE(sb*2 + 1);
    __syncthreads();
  }
#undef STAGE
#undef CTILE
#undef HALF
#undef CVTPK
#undef PSWAP32
#undef PSWAP16

  float sA = la0a[0]+la0a[1]+la0a[2]+la0a[3] + la1a[0]+la1a[1]+la1a[2]+la1a[3];
  float sB = la0b[0]+la0b[1]+la0b[2]+la0b[3] + la1b[0]+la1b[1]+la1b[2]+la1b[3];
  sA += __shfl_xor(sA, 16, 64); sA += __shfl_xor(sA, 32, 64);
  sB += __shfl_xor(sB, 16, 64); sB += __shfl_xor(sB, 32, 64);

  int grow = bh*LQ + qt*128 + w*32;
  size_t base = (size_t)ks*NQROWS;
  if (lane < 16) {
    Pl[base + grow + n16]      = sA;
    Pl[base + grow + 16 + n16] = sB;
  }

  int gqa = grow + quad*4;
#pragma unroll
  for (int r = 0; r < 4; ++r) {
    size_t gq = base + gqa + r;
    ushort_t* pw = Pacc + gq*40;
    pw[n16]      = f2bf(o0a[r]);
    pw[16 + n16] = f2bf(o1a[r]);
    if (n16 < 8) pw[32 + n16] = f2bf(o2a[r]);
    size_t gq2 = gq + 16;
    ushort_t* pw2 = Pacc + gq2*40;
    pw2[n16]      = f2bf(o0b[r]);
    pw2[16 + n16] = f2bf(o1b[r]);
    if (n16 < 8) pw2[32 + n16] = f2bf(o2b[r]);
  }
}

extern "C" void kernel_launch(void* const* d_in, const int* in_sizes, int n_in,
                              void* d_out, int out_size, void* d_ws, size_t ws_size,
                              hipStream_t stream) {
  const float* hidden = (const float*)d_in[0];
  // d_in[1] encoder_hidden_states: UNUSED (softmax rows sum to 1 -> cross == vH)
  const float* ln1_g = (const float*)d_in[2];
  const float* ln1_b = (const float*)d_in[3];
  const float* wq1   = (const float*)d_in[4];
  const float* wk1   = (const float*)d_in[5];
  const float* wv1   = (const float*)d_in[6];
  const float* wo1   = (const float*)d_in[7];
  const float* bo1   = (const float*)d_in[8];
  const float* ln2_g = (const float*)d_in[9];
  const float* ln2_b = (const float*)d_in[10];
  // d_in[11] wq2, d_in[12] wk2: UNUSED
  const float* wvh   = (const float*)d_in[13];
  const float* wo2   = (const float*)d_in[14];
  const float* bo2   = (const float*)d_in[15];
  const float* ln3_g = (const float*)d_in[16];
  const float* ln3_b = (const float*)d_in[17];
  const float* wff1  = (const float*)d_in[18];
  const float* bff1  = (const float*)d_in[19];
  const float* wff2  = (const float*)d_in[20];
  const float* bff2  = (const float*)d_in[21];
  float* out = (float*)d_out;

  // workspace: bf16 region (shorts) then fp32 region
  ushort_t* wsu = (ushort_t*)d_ws;
  ushort_t* wbf   = wsu;                          // WBF_TOTAL shorts
  ushort_t* lnb   = wbf + WBF_TOTAL;              // 4096*320
  ushort_t* Qb    = lnb + (size_t)MROWS*DIM;      // 4096*320
  ushort_t* gegb  = Qb + (size_t)MROWS*DIM;       // 4096*1280
  ushort_t* wct   = gegb + (size_t)MROWS*FFD;     // Wctb: 320*320 (k-blocked)
  ushort_t* vtb   = wct + 320*320;                // Vimg: 16*64*1536
  ushort_t* kpb   = vtb + (size_t)16*64*1536;     // Kimg: 16*64*2048
  ushort_t* Pacc  = kpb + (size_t)16*64*2048;     // KSPLIT*32768*40 bf16
  float* fws = (float*)((((uintptr_t)(Pacc + (size_t)KSPLIT*NQROWS*40)) + 255) & ~(uintptr_t)255);
  float* h2   = fws;                              // 4096*320
  float* Pl   = h2 + (size_t)MROWS*DIM;           // KSPLIT*32768

  dim3 t256(256);
  dim3 gconv(1024, 11);  // y==8: Kimg pad zero; y==9: ln1; y==10: Wc GEMM
  dim3 gqkv(15, 32);
  dim3 g320(5, 64);      // 64-row tiles: 320 blocks >= 256 CUs
  dim3 gffg(20, 32);
  dim3 gattn(16*16*KSPLIT);   // 512 blocks = exactly 2/CU, one pass

  // 1: weights (wo1 -> k-image) + Kimg pad-zero + ln1 + Wc GEMM (fp32 inputs)
  convw_kernel<<<gconv, t256, 0, stream>>>(wq1, wk1, wv1, wo1, wo2, wff1, wff2,
                                           wvh, wbf, kpb, hidden, ln1_g, ln1_b,
                                           lnb, wct);

  // 2-3: self-attention (partials only; merge folded into o1cross_ln)
  mgemm128_qkv<<<gqkv, t256, 0, stream>>>(lnb, wbf + OFF_WQKVT, Qb, kpb, vtb);
  attn_mfma<<<gattn, t256, 0, stream>>>(Qb, kpb, vtb, Pl, Pacc);

  // 4: fused merge + o1 + ln2 + cross + ln3  (attnb/h1 never touch memory)
  o1cross_ln<<<MROWS/16, t256, 0, stream>>>(Pl, Pacc, wbf + OFF_WO1T, bo1,
                                            hidden, ln2_g, ln2_b, wct, bo2,
                                            ln3_g, ln3_b, h2, lnb);

  // 5-6: GEGLU FF
  ff1_geglu<<<gffg, t256, 0, stream>>>(lnb, wbf + OFF_WFF1T, bff1, gegb);
  mgemm<<<g320, t256, 0, stream>>>(gegb, FFD, wbf + OFF_WFF2T, FFD, bff2, h2,
                                   out, nullptr, DIM, FFD);
}

// Round 21
// 194.022 us; speedup vs baseline: 1.0276x; 1.0276x over previous
//
#include <hip/hip_runtime.h>
#include <math.h>

// Problem constants
#define DIM   320
#define HD    40
#define NH    8
#define LQ    2048
#define BATCH 2
#define MROWS 4096
#define FFD   1280
#define FF2   2560

#define KSPLIT 2
#define KCHUNK (LQ/KSPLIT) // 1024
#define KT     32
#define NT     (KCHUNK/KT) // 32 tiles per block
#define NQROWS (BATCH*NH*LQ)  // 32768

#define LSCALE (0.15811388300841897f * 1.4426950408889634f)

typedef unsigned short ushort_t;
typedef unsigned int u32;
using bf16x8 = __attribute__((ext_vector_type(8))) short;
using f32x4  = __attribute__((ext_vector_type(4))) float;

#define AS1 __attribute__((address_space(1)))
#define AS3 __attribute__((address_space(3)))

static __device__ inline ushort_t f2bf(float f) {
  union { float f; unsigned u; } x{f};
  unsigned r = x.u + 0x7FFFu + ((x.u >> 16) & 1u);
  return (ushort_t)(r >> 16);
}
static __device__ inline float bf2f(ushort_t h) {
  union { unsigned u; float f; } x; x.u = ((unsigned)h) << 16; return x.f;
}

// ---------------- Weight convert/transpose to bf16 --------------------------
// R33: REVERT to R31 (196.3us best). R32's e==10 Wc-GEMM branch added 22.6 KB
// unconditional static LDS to every convw block, cutting occupancy of the
// whole ~10K-block conversion grid (+3us net). wc_gemm stays separate.
#define OFF_WQKVT 0
#define OFF_WO1T  (960*320)
#define OFF_WO2T  (OFF_WO1T + 320*320)
#define OFF_WFF1T (OFF_WO2T + 320*320)
#define OFF_WFF2T (OFF_WFF1T + 320*2560)
#define OFF_WVHB  (OFF_WFF2T + 1280*320)
#define WBF_TOTAL (OFF_WVHB + 320*320)

#define AST 72

__global__ __launch_bounds__(256) void convw_kernel(
    const float* __restrict__ wq1, const float* __restrict__ wk1,
    const float* __restrict__ wv1, const float* __restrict__ wo1,
    const float* __restrict__ wo2, const float* __restrict__ wff1,
    const float* __restrict__ wff2, const float* __restrict__ wvh,
    ushort_t* __restrict__ dst, ushort_t* __restrict__ Kimg,
    const float* __restrict__ hidden, const float* __restrict__ ln1_g,
    const float* __restrict__ ln1_b, ushort_t* __restrict__ lnb)
{
  int e = blockIdx.y;
  if (e == 8) {                  // zero Kimg pad chunks: 16bh x 64t x 32rr x 3
    int f = blockIdx.x*256 + threadIdx.x;
    if (f < 98304) {
      int g3 = f/3, cidx = f - 3*g3;
      int rr = g3 & 31, tile_ = (g3 >> 5) & 63, bh = g3 >> 11;
      uint4 z = {0,0,0,0};
      *(uint4*)(Kimg + ((size_t)(bh*64 + tile_))*2048 + rr*64
                + (((5+cidx) ^ (rr&7)) << 3)) = z;
    }
    return;
  }
  if (e == 9) {                  // ln1: one wave per row
    int row  = blockIdx.x * 4 + (threadIdx.x >> 6);
    int lane = threadIdx.x & 63;
    const float* x = hidden + (size_t)row * DIM;
    float v[5];
    float s = 0.f;
#pragma unroll
    for (int i = 0; i < 5; ++i) { v[i] = x[lane + 64*i]; s += v[i]; }
#pragma unroll
    for (int off = 32; off >= 1; off >>= 1) s += __shfl_xor(s, off, 64);
    float mean = s * (1.0f/DIM);
    float sq = 0.f;
#pragma unroll
    for (int i = 0; i < 5; ++i) { float d = v[i] - mean; sq += d*d; }
#pragma unroll
    for (int off = 32; off >= 1; off >>= 1) sq += __shfl_xor(sq, off, 64);
    float rstd = rsqrtf(sq*(1.0f/DIM) + 1e-5f);
    ushort_t* y = lnb + (size_t)row * DIM;
#pragma unroll
    for (int i = 0; i < 5; ++i) {
      int c = lane + 64*i;
      y[c] = f2bf((v[i]-mean)*rstd*ln1_g[c] + ln1_b[c]);
    }
    return;
  }
  const float* src; int K, N; size_t doff; int tr = 1; float scale = 1.f;
  switch (e) {
    case 0: src=wq1;  K=320;  N=320;  doff=OFF_WQKVT; scale=LSCALE; break;
    case 1: src=wk1;  K=320;  N=320;  doff=OFF_WQKVT + 320*320;  break;
    case 2: src=wv1;  K=320;  N=320;  doff=OFF_WQKVT + 2*320*320;break;
    case 3: src=wo1;  K=320;  N=320;  doff=OFF_WO1T; tr=2;       break;
    case 4: src=wo2;  K=320;  N=320;  doff=OFF_WO2T;             break;
    case 5: src=wff1; K=320;  N=2560; doff=OFF_WFF1T;            break;
    case 6: src=wff2; K=1280; N=320;  doff=OFF_WFF2T;            break;
    default: src=wvh; K=320;  N=320;  doff=OFF_WVHB; tr=0;       break;
  }
  int ntN = N/32;
  int nt_total = (K/32)*ntN;
  int t = blockIdx.x;
  if (t >= nt_total) return;
  int kt = t / ntN, nt = t - kt*ntN;
  __shared__ float tile[32][33];
  int tx = threadIdx.x & 31, ty = threadIdx.x >> 5;
  ushort_t* d = dst + doff;
#pragma unroll
  for (int i = 0; i < 4; ++i) {
    int r = ty + 8*i;
    tile[r][tx] = src[(size_t)(kt*32+r)*N + nt*32+tx] * scale;
  }
  __syncthreads();
  if (tr == 1) {
#pragma unroll
    for (int i = 0; i < 4; ++i) {
      int r = ty + 8*i;
      d[(size_t)(nt*32+r)*K + kt*32+tx] = f2bf(tile[tx][r]);
    }
  } else if (tr == 2) {   // k-blocked swizzled B-image: element (k, c)
#pragma unroll
    for (int i = 0; i < 4; ++i) {
      int r = ty + 8*i;
      int k = kt*32 + r, c = nt*32 + tx;
      d[((size_t)kt*320 + c)*32 + ((((k >> 3) & 3) ^ (c & 3)) << 3) + (k & 7)]
          = f2bf(tile[r][tx]);
    }
  } else {
#pragma unroll
    for (int i = 0; i < 4; ++i) {
      int r = ty + 8*i;
      d[(size_t)(kt*32+r)*N + nt*32+tx] = f2bf(tile[r][tx]);
    }
  }
}

// ---------------- bf16 MFMA GEMM (TN), 64x64 tile, BK=64 — ff2 only ---------
__global__ __launch_bounds__(256) void mgemm(
    const ushort_t* __restrict__ A, int lda,
    const ushort_t* __restrict__ Bt, int ldb,
    const float* __restrict__ bias,
    const float* __restrict__ R,
    float* __restrict__ Cf, ushort_t* __restrict__ Cb, int ldc,
    int K)
{
  __shared__ ushort_t As[64*AST];
  __shared__ ushort_t Bs[64*AST];
  int tid = threadIdx.x;
  int w = tid >> 6, lane = tid & 63, quad = lane >> 4, n16 = lane & 15;
  int wm = w >> 1, wn = w & 1;
  int bm = blockIdx.y * 64, bn = blockIdx.x * 64;
  int sr = tid >> 2, sc = (tid & 3) << 4;
  const ushort_t* Ag = A  + (size_t)(bm + sr)*lda + sc;
  const ushort_t* Bg = Bt + (size_t)(bn + sr)*ldb + sc;

  f32x4 acc00 = {0.f,0.f,0.f,0.f}, acc01 = acc00, acc10 = acc00, acc11 = acc00;

  float4 av0 = *(const float4*)(Ag);
  float4 av1 = *(const float4*)(Ag + 8);
  float4 bv0 = *(const float4*)(Bg);
  float4 bv1 = *(const float4*)(Bg + 8);
  for (int k0 = 0; k0 < K; k0 += 64) {
    __syncthreads();
    *(float4*)(As + sr*AST + sc)     = av0;
    *(float4*)(As + sr*AST + sc + 8) = av1;
    *(float4*)(Bs + sr*AST + sc)     = bv0;
    *(float4*)(Bs + sr*AST + sc + 8) = bv1;
    __syncthreads();
    if (k0 + 64 < K) {
      av0 = *(const float4*)(Ag + k0 + 64);
      av1 = *(const float4*)(Ag + k0 + 72);
      bv0 = *(const float4*)(Bg + k0 + 64);
      bv1 = *(const float4*)(Bg + k0 + 72);
    }
#pragma unroll
    for (int kk = 0; kk < 64; kk += 32) {
      bf16x8 fa0 = *(const bf16x8*)(As + (wm*32 +      n16)*AST + kk + quad*8);
      bf16x8 fa1 = *(const bf16x8*)(As + (wm*32 + 16 + n16)*AST + kk + quad*8);
      bf16x8 fb0 = *(const bf16x8*)(Bs + (wn*32 +      n16)*AST + kk + quad*8);
      bf16x8 fb1 = *(const bf16x8*)(Bs + (wn*32 + 16 + n16)*AST + kk + quad*8);
      acc00 = __builtin_amdgcn_mfma_f32_16x16x32_bf16(fa0, fb0, acc00, 0,0,0);
      acc01 = __builtin_amdgcn_mfma_f32_16x16x32_bf16(fa0, fb1, acc01, 0,0,0);
      acc10 = __builtin_amdgcn_mfma_f32_16x16x32_bf16(fa1, fb0, acc10, 0,0,0);
      acc11 = __builtin_amdgcn_mfma_f32_16x16x32_bf16(fa1, fb1, acc11, 0,0,0);
    }
  }

  f32x4 accs[2][2] = {{acc00, acc01},{acc10, acc11}};
#pragma unroll
  for (int s = 0; s < 2; ++s)
#pragma unroll
    for (int t = 0; t < 2; ++t) {
      int c = bn + wn*32 + t*16 + n16;
      float bb = bias ? bias[c] : 0.f;
#pragma unroll
      for (int i = 0; i < 4; ++i) {
        int r = bm + wm*32 + s*16 + quad*4 + i;
        float v = accs[s][t][i] + bb;
        if (R)  v += R[(size_t)r*ldc + c];
        if (Cf) Cf[(size_t)r*ldc + c] = v;
        if (Cb) Cb[(size_t)r*ldc + c] = f2bf(v);
      }
    }
}

// -------- Wc GEMM: Wc^T = wo2^T @ wvh^T, stored k-blocked + swizzled --------
__global__ __launch_bounds__(256) void wc_gemm(
    const ushort_t* __restrict__ A, const ushort_t* __restrict__ Bt,
    ushort_t* __restrict__ Wctb)
{
  __shared__ ushort_t As[64*AST];
  __shared__ ushort_t Bs[64*AST];
  int tid = threadIdx.x;
  int w = tid >> 6, lane = tid & 63, quad = lane >> 4, n16 = lane & 15;
  int wm = w >> 1, wn = w & 1;
  int bm = blockIdx.y * 64, bn = blockIdx.x * 64;
  int sr = tid >> 2, sc = (tid & 3) << 4;
  const ushort_t* Ag = A  + (size_t)(bm + sr)*DIM + sc;
  const ushort_t* Bg = Bt + (size_t)(bn + sr)*DIM + sc;

  f32x4 acc00 = {0.f,0.f,0.f,0.f}, acc01 = acc00, acc10 = acc00, acc11 = acc00;

  float4 av0 = *(const float4*)(Ag);
  float4 av1 = *(const float4*)(Ag + 8);
  float4 bv0 = *(const float4*)(Bg);
  float4 bv1 = *(const float4*)(Bg + 8);
  for (int k0 = 0; k0 < DIM; k0 += 64) {
    __syncthreads();
    *(float4*)(As + sr*AST + sc)     = av0;
    *(float4*)(As + sr*AST + sc + 8) = av1;
    *(float4*)(Bs + sr*AST + sc)     = bv0;
    *(float4*)(Bs + sr*AST + sc + 8) = bv1;
    __syncthreads();
    if (k0 + 64 < DIM) {
      av0 = *(const float4*)(Ag + k0 + 64);
      av1 = *(const float4*)(Ag + k0 + 72);
      bv0 = *(const float4*)(Bg + k0 + 64);
      bv1 = *(const float4*)(Bg + k0 + 72);
    }
#pragma unroll
    for (int kk = 0; kk < 64; kk += 32) {
      bf16x8 fa0 = *(const bf16x8*)(As + (wm*32 +      n16)*AST + kk + quad*8);
      bf16x8 fa1 = *(const bf16x8*)(As + (wm*32 + 16 + n16)*AST + kk + quad*8);
      bf16x8 fb0 = *(const bf16x8*)(Bs + (wn*32 +      n16)*AST + kk + quad*8);
      bf16x8 fb1 = *(const bf16x8*)(Bs + (wn*32 + 16 + n16)*AST + kk + quad*8);
      acc00 = __builtin_amdgcn_mfma_f32_16x16x32_bf16(fa0, fb0, acc00, 0,0,0);
      acc01 = __builtin_amdgcn_mfma_f32_16x16x32_bf16(fa0, fb1, acc01, 0,0,0);
      acc10 = __builtin_amdgcn_mfma_f32_16x16x32_bf16(fa1, fb0, acc10, 0,0,0);
      acc11 = __builtin_amdgcn_mfma_f32_16x16x32_bf16(fa1, fb1, acc11, 0,0,0);
    }
  }

  f32x4 accs[2][2] = {{acc00, acc01},{acc10, acc11}};
#pragma unroll
  for (int s = 0; s < 2; ++s)
#pragma unroll
    for (int t = 0; t < 2; ++t) {
      int c = bn + wn*32 + t*16 + n16;     // k of cross
#pragma unroll
      for (int i = 0; i < 4; ++i) {
        int r = bm + wm*32 + s*16 + quad*4 + i;   // cross output col
        Wctb[((size_t)(c >> 5)*320 + r)*32
             + ((((c >> 3) & 3) ^ (r & 3)) << 3) + (c & 7)] = f2bf(accs[s][t][i]);
      }
    }
}

// -------- fused merge + o1 + ln2 + cross + ln3 (R31) ------------------------
__global__ __launch_bounds__(256) void o1cross_ln(
    const float* __restrict__ Pl, const ushort_t* __restrict__ Pacc,
    const ushort_t* __restrict__ Wo1tb,
    const float* __restrict__ bo1, const float* __restrict__ hidden,
    const float* __restrict__ g2, const float* __restrict__ b2,
    const ushort_t* __restrict__ Wctb, const float* __restrict__ bo2,
    const float* __restrict__ g3, const float* __restrict__ b3,
    float* __restrict__ h2, ushort_t* __restrict__ lnb)
{
  __shared__ ushort_t Asm[16*328];      // 10.25 KB
  __shared__ ushort_t Bsm[2*10240];     // 40 KB, double-buffered 32-k slabs
  __shared__ float    sred[4][16][2];
  __shared__ float    fstat[16][2];
  int tid = threadIdx.x;
  int w = tid >> 6, lane = tid & 63, quad = lane >> 4, n16 = lane & 15;
  int r0 = blockIdx.x * 16;

  // ---- Phase A: inline KSPLIT=2 merge -> normalized attn rows into Asm ----
  {
    int ar = tid >> 4, aj = tid & 15;
    int r = r0 + ar;
    int b = r >> 11, qi = r & (LQ-1);
    int h = aj >> 1, off = (aj & 1)*20;
    size_t idx = (size_t)(b*8 + h)*LQ + qi;
    float L = Pl[idx] + Pl[(size_t)NQROWS + idx];
    float inv = 1.0f / L;
    const ushort_t* p0 = Pacc + idx*40 + off;
    const ushort_t* p1 = Pacc + ((size_t)NQROWS + idx)*40 + off;
    ushort_t tb[20];
#pragma unroll
    for (int i = 0; i < 5; ++i) {
      ushort_t b0[4], b1[4];
      *(uint2*)b0 = *(const uint2*)(p0 + 4*i);
      *(uint2*)b1 = *(const uint2*)(p1 + 4*i);
#pragma unroll
      for (int j = 0; j < 4; ++j)
        tb[4*i+j] = f2bf((bf2f(b0[j]) + bf2f(b1[j])) * inv);
    }
#pragma unroll
    for (int i = 0; i < 5; ++i)
      *(uint2*)(Asm + ar*328 + aj*20 + 4*i) = *(uint2*)(tb + 4*i);
  }

#define STAGEB(BASE, BUF, KB) { \
  const ushort_t* src_ = (BASE) + (size_t)(KB)*10240; \
  _Pragma("unroll") \
  for (int i = 0; i < 5; ++i) { \
    __builtin_amdgcn_global_load_lds( \
        (const AS1 u32*)(src_ + i*2048 + w*512 + lane*8), \
        (AS3 u32*)(Bsm + (BUF)*10240 + i*2048 + w*512), 16, 0, 0); \
  } }

  f32x4 acc[5];
#pragma unroll
  for (int t = 0; t < 5; ++t) acc[t] = f32x4{0.f,0.f,0.f,0.f};

  // ---- GEMM1: attn @ wo1-image ----
  STAGEB(Wo1tb, 0, 0);
  __syncthreads();              // Asm written (lgkm) + slab0 (vmcnt)
  int bbuf = 0;
  for (int kb = 0; kb < 10; ++kb) {
    if (kb + 1 < 10) STAGEB(Wo1tb, bbuf^1, kb + 1);
    const ushort_t* Bb = Bsm + bbuf*10240;
    bf16x8 fa = *(const bf16x8*)(Asm + n16*328 + kb*32 + quad*8);
#pragma unroll
    for (int t = 0; t < 5; ++t) {
      int c = w*80 + t*16 + n16;
      bf16x8 fb = *(const bf16x8*)(Bb + c*32 + ((quad ^ (c & 3)) << 3));
      acc[t] = __builtin_amdgcn_mfma_f32_16x16x32_bf16(fa, fb, acc[t], 0,0,0);
    }
    __syncthreads();
    bbuf ^= 1;
  }

  // issue Wc slab 0 early (drained by the pre-GEMM2 barrier)
  STAGEB(Wctb, 0, 0);

  // ---- Epilogue1: h1 = acc + bo1 + hidden (registers); ln2 stats ----
  float h1v[5][4];
  float ss[4] = {0,0,0,0}, qq[4] = {0,0,0,0};
#pragma unroll
  for (int t = 0; t < 5; ++t) {
    int c = w*80 + t*16 + n16;
    float bb = bo1[c];
#pragma unroll
    for (int i = 0; i < 4; ++i) {
      int r = r0 + quad*4 + i;
      float v = acc[t][i] + bb + hidden[(size_t)r*DIM + c];
      h1v[t][i] = v;
      ss[i] += v; qq[i] += v*v;
    }
  }
#pragma unroll
  for (int off = 1; off < 16; off <<= 1)
#pragma unroll
    for (int i = 0; i < 4; ++i) {
      ss[i] += __shfl_xor(ss[i], off, 64);
      qq[i] += __shfl_xor(qq[i], off, 64);
    }
  if (n16 == 0)
#pragma unroll
    for (int i = 0; i < 4; ++i) {
      sred[w][quad*4 + i][0] = ss[i];
      sred[w][quad*4 + i][1] = qq[i];
    }
  __syncthreads();
  if (tid < 16) {
    float S = sred[0][tid][0]+sred[1][tid][0]+sred[2][tid][0]+sred[3][tid][0];
    float Q = sred[0][tid][1]+sred[1][tid][1]+sred[2][tid][1]+sred[3][tid][1];
    float mm = S*(1.f/DIM);
    fstat[tid][0] = mm;
    fstat[tid][1] = rsqrtf(fmaxf(Q*(1.f/DIM) - mm*mm, 0.f) + 1e-5f);
  }
  __syncthreads();
  // write ln2(h1) bf16 into Asm (fragment-scattered b16 stores)
#pragma unroll
  for (int t = 0; t < 5; ++t) {
    int c = w*80 + t*16 + n16;
    float gg = g2[c], bbv = b2[c];
#pragma unroll
    for (int i = 0; i < 4; ++i) {
      int rr = quad*4 + i;
      Asm[rr*328 + c] = f2bf((h1v[t][i] - fstat[rr][0])*fstat[rr][1]*gg + bbv);
    }
  }
#pragma unroll
  for (int t = 0; t < 5; ++t) acc[t] = f32x4{0.f,0.f,0.f,0.f};
  __syncthreads();              // Asm ln2 writes visible + Wc slab0 staged

  // ---- GEMM2: ln2(h1) @ Wc-image ----
  bbuf = 0;
  for (int kb = 0; kb < 10; ++kb) {
    if (kb + 1 < 10) STAGEB(Wctb, bbuf^1, kb + 1);
    const ushort_t* Bb = Bsm + bbuf*10240;
    bf16x8 fa = *(const bf16x8*)(Asm + n16*328 + kb*32 + quad*8);
#pragma unroll
    for (int t = 0; t < 5; ++t) {
      int c = w*80 + t*16 + n16;
      bf16x8 fb = *(const bf16x8*)(Bb + c*32 + ((quad ^ (c & 3)) << 3));
      acc[t] = __builtin_amdgcn_mfma_f32_16x16x32_bf16(fa, fb, acc[t], 0,0,0);
    }
    __syncthreads();
    bbuf ^= 1;
  }
#undef STAGEB

  // ---- Epilogue2: h2 = acc + bo2 + h1; ln3 stats; write h2 fp32, lnb bf16 --
  float hv[5][4];
  float ss2[4] = {0,0,0,0}, qq2[4] = {0,0,0,0};
#pragma unroll
  for (int t = 0; t < 5; ++t) {
    int c = w*80 + t*16 + n16;
    float bb = bo2[c];
#pragma unroll
    for (int i = 0; i < 4; ++i) {
      int r = r0 + quad*4 + i;
      float v = acc[t][i] + bb + h1v[t][i];
      hv[t][i] = v;
      h2[(size_t)r*DIM + c] = v;
      ss2[i] += v; qq2[i] += v*v;
    }
  }
#pragma unroll
  for (int off = 1; off < 16; off <<= 1)
#pragma unroll
    for (int i = 0; i < 4; ++i) {
      ss2[i] += __shfl_xor(ss2[i], off, 64);
      qq2[i] += __shfl_xor(qq2[i], off, 64);
    }
  if (n16 == 0)
#pragma unroll
    for (int i = 0; i < 4; ++i) {
      sred[w][quad*4 + i][0] = ss2[i];
      sred[w][quad*4 + i][1] = qq2[i];
    }
  __syncthreads();
  if (tid < 16) {
    float S = sred[0][tid][0]+sred[1][tid][0]+sred[2][tid][0]+sred[3][tid][0];
    float Q = sred[0][tid][1]+sred[1][tid][1]+sred[2][tid][1]+sred[3][tid][1];
    float mm = S*(1.f/DIM);
    fstat[tid][0] = mm;
    fstat[tid][1] = rsqrtf(fmaxf(Q*(1.f/DIM) - mm*mm, 0.f) + 1e-5f);
  }
  __syncthreads();
#pragma unroll
  for (int t = 0; t < 5; ++t) {
    int c = w*80 + t*16 + n16;
    float gg = g3[c], bb = b3[c];
#pragma unroll
    for (int i = 0; i < 4; ++i) {
      int rr = quad*4 + i;
      lnb[(size_t)(r0 + rr)*DIM + c] =
          f2bf((hv[t][i] - fstat[rr][0])*fstat[rr][1]*gg + bb);
    }
  }
}

// --------- qkv GEMM 128x64 + fused K/V-image epilogue (R19, R21: BK=64) -----
__global__ __launch_bounds__(256) void mgemm128_qkv(
    const ushort_t* __restrict__ A, const ushort_t* __restrict__ Bt,
    ushort_t* __restrict__ Qb, ushort_t* __restrict__ Kimg,
    ushort_t* __restrict__ Vimg)
{
  __shared__ ushort_t As[128*AST];   // 18 KB
  __shared__ ushort_t Bs[64*AST];    // 9 KB
  int tid = threadIdx.x;
  int w = tid >> 6, lane = tid & 63, quad = lane >> 4, n16 = lane & 15;
  int wm = w >> 1, wn = w & 1;
  int bm = blockIdx.y * 128, bn = blockIdx.x * 64;
  int ar = tid >> 2, ac = (tid & 3) << 4;
  const ushort_t* Ag0 = A  + (size_t)(bm + ar)*DIM + ac;
  const ushort_t* Ag1 = A  + (size_t)(bm + 64 + ar)*DIM + ac;
  const ushort_t* Bg  = Bt + (size_t)(bn + ar)*DIM + ac;

  f32x4 acc[4][2];
#pragma unroll
  for (int s = 0; s < 4; ++s)
#pragma unroll
    for (int t = 0; t < 2; ++t) acc[s][t] = f32x4{0.f,0.f,0.f,0.f};

  float4 a00 = *(const float4*)(Ag0);
  float4 a01 = *(const float4*)(Ag0 + 8);
  float4 a10 = *(const float4*)(Ag1);
  float4 a11 = *(const float4*)(Ag1 + 8);
  float4 b0  = *(const float4*)(Bg);
  float4 b1  = *(const float4*)(Bg + 8);
  for (int k0 = 0; k0 < DIM; k0 += 64) {
    __syncthreads();
    *(float4*)(As + ar*AST + ac)          = a00;
    *(float4*)(As + ar*AST + ac + 8)      = a01;
    *(float4*)(As + (64+ar)*AST + ac)     = a10;
    *(float4*)(As + (64+ar)*AST + ac + 8) = a11;
    *(float4*)(Bs + ar*AST + ac)          = b0;
    *(float4*)(Bs + ar*AST + ac + 8)      = b1;
    __syncthreads();
    if (k0 + 64 < DIM) {
      a00 = *(const float4*)(Ag0 + k0 + 64);
      a01 = *(const float4*)(Ag0 + k0 + 72);
      a10 = *(const float4*)(Ag1 + k0 + 64);
      a11 = *(const float4*)(Ag1 + k0 + 72);
      b0  = *(const float4*)(Bg  + k0 + 64);
      b1  = *(const float4*)(Bg  + k0 + 72);
    }
#pragma unroll
    for (int kk = 0; kk < 64; kk += 32) {
      bf16x8 fa[4], fb[2];
#pragma unroll
      for (int s = 0; s < 4; ++s)
        fa[s] = *(const bf16x8*)(As + (wm*64 + s*16 + n16)*AST + kk + quad*8);
#pragma unroll
      for (int t = 0; t < 2; ++t)
        fb[t] = *(const bf16x8*)(Bs + (wn*32 + t*16 + n16)*AST + kk + quad*8);
#pragma unroll
      for (int s = 0; s < 4; ++s)
#pragma unroll
        for (int t = 0; t < 2; ++t)
          acc[s][t] = __builtin_amdgcn_mfma_f32_16x16x32_bf16(fa[s], fb[t], acc[s][t], 0,0,0);
    }
  }

  int b8 = (bm >> 11) << 3;   // batch*8
  if (bn < 320) {             // ---- Q region -> Qb[r*320 + c]
#pragma unroll
    for (int s = 0; s < 4; ++s)
#pragma unroll
      for (int t = 0; t < 2; ++t) {
        int c = bn + wn*32 + t*16 + n16;
#pragma unroll
        for (int i = 0; i < 4; ++i) {
          int r = bm + wm*64 + s*16 + quad*4 + i;
          Qb[(size_t)r*320 + c] = f2bf(acc[s][t][i]);
        }
      }
  } else if (bn < 640) {      // ---- K region -> Kimg swizzled
#pragma unroll
    for (int t = 0; t < 2; ++t) {
      int c = bn + wn*32 + t*16 + n16 - 320;
      int hK = c / 40, d = c - hK*40;
#pragma unroll
      for (int s = 0; s < 4; ++s)
#pragma unroll
        for (int i = 0; i < 4; ++i) {
          int r = bm + wm*64 + s*16 + quad*4 + i;
          int l = r & 2047, tl = l >> 5, rr = l & 31;
          Kimg[((size_t)((b8 + hK)*64 + tl))*2048 + rr*64
               + (((d >> 3) ^ (rr & 7)) << 3) + (d & 7)] = f2bf(acc[s][t][i]);
        }
    }
  } else {                    // ---- V region -> Vimg swizzled, pair-packed
#pragma unroll
    for (int t = 0; t < 2; ++t) {
      int c = bn + wn*32 + t*16 + n16 - 640;
      int hV = c / 40, d = c - hV*40;
#pragma unroll
      for (int s = 0; s < 4; ++s) {
        int l0 = (bm + wm*64 + s*16 + quad*4) & 2047;
        int tl = l0 >> 5, p0 = (l0 & 31) >> 1;
        ushort_t* vb = Vimg + ((size_t)((b8 + hV)*64 + tl))*1536 + d*32;
#pragma unroll
        for (int j = 0; j < 2; ++j) {
          int p = p0 + j;
          unsigned val = (unsigned)f2bf(acc[s][t][2*j])
                       | ((unsigned)f2bf(acc[s][t][2*j+1]) << 16);
          *(unsigned*)(vb + (((p >> 2) ^ (d & 3)) << 3) + ((p & 3) << 1)) = val;
        }
      }
    }
  }
}

// -------- ff1 GEMM 128x64 + fused GEGLU (R21: BK=64) ------------------------
__global__ __launch_bounds__(256) void ff1_geglu(
    const ushort_t* __restrict__ A, const ushort_t* __restrict__ Bt,
    const float* __restrict__ bias, ushort_t* __restrict__ Og)
{
  __shared__ ushort_t As[128*AST];   // 18 KB
  __shared__ ushort_t Bxs[64*AST];   // 9 KB
  __shared__ ushort_t Bgs[64*AST];   // 9 KB
  int tid = threadIdx.x;
  int w = tid >> 6, lane = tid & 63, quad = lane >> 4, n16 = lane & 15;
  int wm = w >> 1, wn = w & 1;
  int bm = blockIdx.y * 128, bn = blockIdx.x * 64;
  int ar = tid >> 2, ac = (tid & 3) << 4;
  const ushort_t* Ag0 = A  + (size_t)(bm + ar)*DIM + ac;
  const ushort_t* Ag1 = A  + (size_t)(bm + 64 + ar)*DIM + ac;
  const ushort_t* Bxg = Bt + (size_t)(bn + ar)*DIM + ac;
  const ushort_t* Bgg = Bt + (size_t)(bn + FFD + ar)*DIM + ac;

  f32x4 ax[4][2], ag[4][2];
#pragma unroll
  for (int s = 0; s < 4; ++s)
#pragma unroll
    for (int t = 0; t < 2; ++t) { ax[s][t] = f32x4{0.f,0.f,0.f,0.f}; ag[s][t] = ax[s][t]; }

  float4 a00 = *(const float4*)(Ag0);
  float4 a01 = *(const float4*)(Ag0 + 8);
  float4 a10 = *(const float4*)(Ag1);
  float4 a11 = *(const float4*)(Ag1 + 8);
  float4 bx0 = *(const float4*)(Bxg);
  float4 bx1 = *(const float4*)(Bxg + 8);
  float4 bg0 = *(const float4*)(Bgg);
  float4 bg1 = *(const float4*)(Bgg + 8);
  for (int k0 = 0; k0 < DIM; k0 += 64) {
    __syncthreads();
    *(float4*)(As  + ar*AST + ac)          = a00;
    *(float4*)(As  + ar*AST + ac + 8)      = a01;
    *(float4*)(As  + (64+ar)*AST + ac)     = a10;
    *(float4*)(As  + (64+ar)*AST + ac + 8) = a11;
    *(float4*)(Bxs + ar*AST + ac)          = bx0;
    *(float4*)(Bxs + ar*AST + ac + 8)      = bx1;
    *(float4*)(Bgs + ar*AST + ac)          = bg0;
    *(float4*)(Bgs + ar*AST + ac + 8)      = bg1;
    __syncthreads();
    if (k0 + 64 < DIM) {
      a00 = *(const float4*)(Ag0 + k0 + 64);
      a01 = *(const float4*)(Ag0 + k0 + 72);
      a10 = *(const float4*)(Ag1 + k0 + 64);
      a11 = *(const float4*)(Ag1 + k0 + 72);
      bx0 = *(const float4*)(Bxg + k0 + 64);
      bx1 = *(const float4*)(Bxg + k0 + 72);
      bg0 = *(const float4*)(Bgg + k0 + 64);
      bg1 = *(const float4*)(Bgg + k0 + 72);
    }
#pragma unroll
    for (int kk = 0; kk < 64; kk += 32) {
      bf16x8 fa[4], fx[2], fg[2];
#pragma unroll
      for (int s = 0; s < 4; ++s)
        fa[s] = *(const bf16x8*)(As + (wm*64 + s*16 + n16)*AST + kk + quad*8);
#pragma unroll
      for (int t = 0; t < 2; ++t) {
        fx[t] = *(const bf16x8*)(Bxs + (wn*32 + t*16 + n16)*AST + kk + quad*8);
        fg[t] = *(const bf16x8*)(Bgs + (wn*32 + t*16 + n16)*AST + kk + quad*8);
      }
#pragma unroll
      for (int s = 0; s < 4; ++s)
#pragma unroll
        for (int t = 0; t < 2; ++t) {
          ax[s][t] = __builtin_amdgcn_mfma_f32_16x16x32_bf16(fa[s], fx[t], ax[s][t], 0,0,0);
          ag[s][t] = __builtin_amdgcn_mfma_f32_16x16x32_bf16(fa[s], fg[t], ag[s][t], 0,0,0);
        }
    }
  }

  const float kk2 = 0.7071067811865476f;
#pragma unroll
  for (int s = 0; s < 4; ++s)
#pragma unroll
    for (int t = 0; t < 2; ++t) {
      int c = bn + wn*32 + t*16 + n16;
      float bx = bias[c], bg = bias[c + FFD];
#pragma unroll
      for (int i = 0; i < 4; ++i) {
        int r = bm + wm*64 + s*16 + quad*4 + i;
        float xx = ax[s][t][i] + bx;
        float gg = ag[s][t][i] + bg;
        Og[(size_t)r*FFD + c] = f2bf(xx * 0.5f * gg * (1.f + erff(gg * kk2)));
      }
    }
}

// ---------------- MFMA flash attention (R20 super-stage, KSPLIT=2) ----------
#define TILE_K_SH 2048
#define TILE_V_SH 1536
#define TILE_SH   (TILE_K_SH + TILE_V_SH)

__global__ __launch_bounds__(256, 2) void attn_mfma(
    const ushort_t* __restrict__ Qb, const ushort_t* __restrict__ Kimg,
    const ushort_t* __restrict__ Vimg,
    float* __restrict__ Pl, ushort_t* __restrict__ Pacc)
{
  __shared__ ushort_t lds[4*TILE_SH];      // 28672 B, 4 tile-slots
  int tid  = threadIdx.x;
  int w    = tid >> 6;
  int lane = tid & 63;
  int quad = lane >> 4;
  int n16  = lane & 15;

  int blk  = blockIdx.x;
  int bh   = (blk & 7) | (((blk >> 3) & 1) << 3);
  int rest = blk >> 4;
  int qt   = rest & 15;
  int ks   = rest >> 4;           // 0..KSPLIT-1
  int b = bh >> 3, h = bh & 7;

  const ushort_t* qrowa = Qb + (size_t)(b*LQ + qt*128 + w*32 + n16)*320 + h*HD;
  const ushort_t* qrowb = qrowa + 16*320;
  bf16x8 qf0a = *(const bf16x8*)(qrowa + quad*8);
  bf16x8 qf1a = *(const bf16x8*)(qrowa + 32);
  bf16x8 qf0b = *(const bf16x8*)(qrowb + quad*8);
  bf16x8 qf1b = *(const bf16x8*)(qrowb + 32);

  const ushort_t* Ktb = Kimg + ((size_t)bh*64 + ks*NT)*TILE_K_SH;
  const ushort_t* Vtb = Vimg + ((size_t)bh*64 + ks*NT)*TILE_V_SH;

  int swk0 = (quad ^ (n16 & 7)) << 3;
  int swk1 = ((quad + 4) ^ (n16 & 7)) << 3;
  int kof0 = n16*64 + swk0;
  int kof1 = n16*64 + swk1;
  int kof2 = (16+n16)*64 + swk0;
  int kof3 = (16+n16)*64 + swk1;
  int swv  = (quad ^ (n16 & 3)) << 3;
  int vof0 = n16*32 + swv;
  int vof1 = (16+n16)*32 + swv;
  int vof2 = (32+n16)*32 + swv;

  f32x4 o0a = {0.f,0.f,0.f,0.f}, o1a = o0a, o2a = o0a;
  f32x4 o0b = o0a, o1b = o0a, o2b = o0a;
  f32x4 la0a = o0a, la1a = o0a, la0b = o0a, la1b = o0a;

#define CVTPK(D, LO, HI) \
  asm("v_cvt_pk_bf16_f32 %0, %1, %2" : "=v"(D) : "v"(LO), "v"(HI))
#define PSWAP32(X, Y) \
  asm("v_permlane32_swap_b32 %0, %1" : "+v"(X), "+v"(Y))
#define PSWAP16(X, Y) \
  asm("v_permlane16_swap_b32 %0, %1" : "+v"(X), "+v"(Y))

#define STAGE(SLOT, T) { \
  const ushort_t* ks_ = Ktb + (size_t)(T)*TILE_K_SH + w*512 + lane*8; \
  ushort_t* kd_ = lds + (SLOT)*TILE_SH + w*512; \
  __builtin_amdgcn_global_load_lds( \
      (const AS1 u32*)ks_, (AS3 u32*)kd_, 16, 0, 0); \
  if (w < 3) { \
    const ushort_t* vs_ = Vtb + (size_t)(T)*TILE_V_SH + w*512 + lane*8; \
    ushort_t* vd_ = lds + (SLOT)*TILE_SH + TILE_K_SH + w*512; \
    __builtin_amdgcn_global_load_lds( \
        (const AS1 u32*)vs_, (AS3 u32*)vd_, 16, 0, 0); \
  } }

#define HALF(Q0F, Q1F, LA0, LA1, FRAG) \
  bf16x8 FRAG; { \
  f32x4 st0 = {-8.f,-8.f,-8.f,-8.f}; f32x4 st1 = st0; \
  st0 = __builtin_amdgcn_mfma_f32_16x16x32_bf16(K00, Q0F, st0, 0,0,0); \
  st1 = __builtin_amdgcn_mfma_f32_16x16x32_bf16(K10, Q0F, st1, 0,0,0); \
  st0 = __builtin_amdgcn_mfma_f32_16x16x32_bf16(K01, Q1F, st0, 0,0,0); \
  st1 = __builtin_amdgcn_mfma_f32_16x16x32_bf16(K11, Q1F, st1, 0,0,0); \
  f32x4 p0, p1; \
  _Pragma("unroll") \
  for (int r = 0; r < 4; ++r) { p0[r] = exp2f(st0[r]); p1[r] = exp2f(st1[r]); } \
  LA0 += p0; LA1 += p1; \
  unsigned d0, d1, d2, d3; \
  CVTPK(d0, p0[0], p0[1]); CVTPK(d1, p0[2], p0[3]); \
  CVTPK(d2, p1[0], p1[1]); CVTPK(d3, p1[2], p1[3]); \
  PSWAP32(d0, d2); PSWAP16(d0, d2); \
  PSWAP32(d1, d3); PSWAP16(d1, d3); \
  union { unsigned u[4]; bf16x8 v; } fr_; \
  fr_.u[0] = d0; fr_.u[1] = d1; fr_.u[2] = d2; fr_.u[3] = d3; \
  FRAG = fr_.v; }

#define CTILE(SLOT) { \
  const ushort_t* Kb_ = lds + (SLOT)*TILE_SH; \
  const ushort_t* Vb_ = Kb_ + TILE_K_SH; \
  bf16x8 K00 = *(const bf16x8*)(Kb_ + kof0); \
  bf16x8 K01 = *(const bf16x8*)(Kb_ + kof1); \
  bf16x8 K10 = *(const bf16x8*)(Kb_ + kof2); \
  bf16x8 K11 = *(const bf16x8*)(Kb_ + kof3); \
  bf16x8 V0  = *(const bf16x8*)(Vb_ + vof0); \
  bf16x8 V1  = *(const bf16x8*)(Vb_ + vof1); \
  bf16x8 V2  = *(const bf16x8*)(Vb_ + vof2); \
  HALF(qf0a, qf1a, la0a, la1a, fragA) \
  HALF(qf0b, qf1b, la0b, la1b, fragB) \
  o0a = __builtin_amdgcn_mfma_f32_16x16x32_bf16(fragA, V0, o0a, 0,0,0); \
  o0b = __builtin_amdgcn_mfma_f32_16x16x32_bf16(fragB, V0, o0b, 0,0,0); \
  o1a = __builtin_amdgcn_mfma_f32_16x16x32_bf16(fragA, V1, o1a, 0,0,0); \
  o1b = __builtin_amdgcn_mfma_f32_16x16x32_bf16(fragB, V1, o1b, 0,0,0); \
  o2a = __builtin_amdgcn_mfma_f32_16x16x32_bf16(fragA, V2, o2a, 0,0,0); \
  o2b = __builtin_amdgcn_mfma_f32_16x16x32_bf16(fragB, V2, o2b, 0,0,0); }

  STAGE(0, 0); STAGE(1, 1);
  __syncthreads();
  for (int s = 0; s < NT/2; ++s) {
    int sb = s & 1;
    if (s + 1 < NT/2) {
      STAGE((sb^1)*2,     2*s + 2);
      STAGE((sb^1)*2 + 1, 2*s + 3);
    }
    CTILE(sb*2);
    CTILE(sb*2 + 1);
    __syncthreads();
  }
#undef STAGE
#undef CTILE
#undef HALF
#undef CVTPK
#undef PSWAP32
#undef PSWAP16

  float sA = la0a[0]+la0a[1]+la0a[2]+la0a[3] + la1a[0]+la1a[1]+la1a[2]+la1a[3];
  float sB = la0b[0]+la0b[1]+la0b[2]+la0b[3] + la1b[0]+la1b[1]+la1b[2]+la1b[3];
  sA += __shfl_xor(sA, 16, 64); sA += __shfl_xor(sA, 32, 64);
  sB += __shfl_xor(sB, 16, 64); sB += __shfl_xor(sB, 32, 64);

  int grow = bh*LQ + qt*128 + w*32;
  size_t base = (size_t)ks*NQROWS;
  if (lane < 16) {
    Pl[base + grow + n16]      = sA;
    Pl[base + grow + 16 + n16] = sB;
  }

  int gqa = grow + quad*4;
#pragma unroll
  for (int r = 0; r < 4; ++r) {
    size_t gq = base + gqa + r;
    ushort_t* pw = Pacc + gq*40;
    pw[n16]      = f2bf(o0a[r]);
    pw[16 + n16] = f2bf(o1a[r]);
    if (n16 < 8) pw[32 + n16] = f2bf(o2a[r]);
    size_t gq2 = gq + 16;
    ushort_t* pw2 = Pacc + gq2*40;
    pw2[n16]      = f2bf(o0b[r]);
    pw2[16 + n16] = f2bf(o1b[r]);
    if (n16 < 8) pw2[32 + n16] = f2bf(o2b[r]);
  }
}

extern "C" void kernel_launch(void* const* d_in, const int* in_sizes, int n_in,
                              void* d_out, int out_size, void* d_ws, size_t ws_size,
                              hipStream_t stream) {
  const float* hidden = (const float*)d_in[0];
  // d_in[1] encoder_hidden_states: UNUSED (softmax rows sum to 1 -> cross == vH)
  const float* ln1_g = (const float*)d_in[2];
  const float* ln1_b = (const float*)d_in[3];
  const float* wq1   = (const float*)d_in[4];
  const float* wk1   = (const float*)d_in[5];
  const float* wv1   = (const float*)d_in[6];
  const float* wo1   = (const float*)d_in[7];
  const float* bo1   = (const float*)d_in[8];
  const float* ln2_g = (const float*)d_in[9];
  const float* ln2_b = (const float*)d_in[10];
  // d_in[11] wq2, d_in[12] wk2: UNUSED
  const float* wvh   = (const float*)d_in[13];
  const float* wo2   = (const float*)d_in[14];
  const float* bo2   = (const float*)d_in[15];
  const float* ln3_g = (const float*)d_in[16];
  const float* ln3_b = (const float*)d_in[17];
  const float* wff1  = (const float*)d_in[18];
  const float* bff1  = (const float*)d_in[19];
  const float* wff2  = (const float*)d_in[20];
  const float* bff2  = (const float*)d_in[21];
  float* out = (float*)d_out;

  // workspace: bf16 region (shorts) then fp32 region
  ushort_t* wsu = (ushort_t*)d_ws;
  ushort_t* wbf   = wsu;                          // WBF_TOTAL shorts
  ushort_t* lnb   = wbf + WBF_TOTAL;              // 4096*320
  ushort_t* Qb    = lnb + (size_t)MROWS*DIM;      // 4096*320
  ushort_t* gegb  = Qb + (size_t)MROWS*DIM;       // 4096*1280
  ushort_t* wct   = gegb + (size_t)MROWS*FFD;     // Wctb: 320*320 (k-blocked)
  ushort_t* vtb   = wct + 320*320;                // Vimg: 16*64*1536
  ushort_t* kpb   = vtb + (size_t)16*64*1536;     // Kimg: 16*64*2048
  ushort_t* Pacc  = kpb + (size_t)16*64*2048;     // KSPLIT*32768*40 bf16
  float* fws = (float*)((((uintptr_t)(Pacc + (size_t)KSPLIT*NQROWS*40)) + 255) & ~(uintptr_t)255);
  float* h2   = fws;                              // 4096*320
  float* Pl   = h2 + (size_t)MROWS*DIM;           // KSPLIT*32768

  dim3 t256(256);
  dim3 gconv(1024, 10);  // y==8: Kimg pad zero; y==9: ln1
  dim3 gqkv(15, 32);
  dim3 g320(5, 64);      // 64-row tiles: 320 blocks >= 256 CUs
  dim3 gwc(5, 5);
  dim3 gffg(20, 32);
  dim3 gattn(16*16*KSPLIT);   // 512 blocks = exactly 2/CU, one pass

  // 1: weights (wo1 -> k-image) + Kimg pad-zero + ln1
  convw_kernel<<<gconv, t256, 0, stream>>>(wq1, wk1, wv1, wo1, wo2, wff1, wff2,
                                           wvh, wbf, kpb, hidden, ln1_g, ln1_b, lnb);
  // 2: Wc^T k-blocked/swizzled image (tiny)
  wc_gemm<<<gwc, t256, 0, stream>>>(wbf + OFF_WO2T, wbf + OFF_WVHB, wct);

  // 3-4: self-attention (partials only; merge folded into o1cross_ln)
  mgemm128_qkv<<<gqkv, t256, 0, stream>>>(lnb, wbf + OFF_WQKVT, Qb, kpb, vtb);
  attn_mfma<<<gattn, t256, 0, stream>>>(Qb, kpb, vtb, Pl, Pacc);

  // 5: fused merge + o1 + ln2 + cross + ln3  (attnb/h1 never touch memory)
  o1cross_ln<<<MROWS/16, t256, 0, stream>>>(Pl, Pacc, wbf + OFF_WO1T, bo1,
                                            hidden, ln2_g, ln2_b, wct, bo2,
                                            ln3_g, ln3_b, h2, lnb);

  // 6-7: GEGLU FF
  ff1_geglu<<<gffg, t256, 0, stream>>>(lnb, wbf + OFF_WFF1T, bff1, gegb);
  mgemm<<<g320, t256, 0, stream>>>(gegb, FFD, wbf + OFF_WFF2T, FFD, bff2, h2,
                                   out, nullptr, DIM, FFD);
}